// Round 5
// baseline (149.457 us; speedup 1.0000x reference)
//
#include <hip/hip_runtime.h>
#include <hip/hip_bf16.h>

typedef __attribute__((ext_vector_type(8))) short short8;
typedef __attribute__((ext_vector_type(4))) short short4v;
typedef __attribute__((ext_vector_type(4))) float f32x4;

#define SC_L2E 0.4561727848849353f          // (1/sqrt(10)) * log2(e)

#if __has_builtin(__builtin_amdgcn_exp2f)
#define EXP2F __builtin_amdgcn_exp2f
#else
#define EXP2F exp2f
#endif

static __device__ __forceinline__ f32x4 mfma16(short4v a, short4v b, f32x4 c) {
#if __has_builtin(__builtin_amdgcn_mfma_f32_16x16x16bf16_1k)
  return __builtin_amdgcn_mfma_f32_16x16x16bf16_1k(a, b, c, 0, 0, 0);
#else
  asm("v_mfma_f32_16x16x16_bf16 %0, %1, %2, %0" : "+v"(c) : "v"(a), "v"(b));
  return c;
#endif
}

static __device__ __forceinline__ void gload16(const void* g, void* l) {
  __builtin_amdgcn_global_load_lds((const __attribute__((address_space(1))) void*)g,
                                   (__attribute__((address_space(3))) void*)l, 16, 0, 0);
}

static __device__ __forceinline__ int pkbf16_pair(float lo, float hi, __hip_bfloat16* out2) {
  out2[0] = __float2bfloat16(lo);
  out2[1] = __float2bfloat16(hi);
  return 0;
}

// ---------------- kernel 1: convert q,k,v fp32 -> bf16 ----------------
__global__ void k_cvt_qkv(const float* __restrict__ q, const float* __restrict__ kk,
                          const float* __restrict__ v, __hip_bfloat16* __restrict__ xb) {
  const size_t i = ((size_t)blockIdx.x * 256 + threadIdx.x) * 8;
  const int t = (int)(i >> 22);                 // 4194304 elements per tensor
  const float* src = (t == 0) ? q : (t == 1) ? kk : v;
  const size_t off = i & 4194303u;
  float4 f0 = *(const float4*)(src + off);
  float4 f1 = *(const float4*)(src + off + 4);
  union { short8 s; __hip_bfloat16 h[8]; } u;
  u.h[0] = __float2bfloat16(f0.x); u.h[1] = __float2bfloat16(f0.y);
  u.h[2] = __float2bfloat16(f0.z); u.h[3] = __float2bfloat16(f0.w);
  u.h[4] = __float2bfloat16(f1.x); u.h[5] = __float2bfloat16(f1.y);
  u.h[6] = __float2bfloat16(f1.z); u.h[7] = __float2bfloat16(f1.w);
  *(short8*)((char*)xb + i * 2) = u.s;
}

// ---------------- kernel 2: convert + transpose weights ----------------
__global__ void k_cvt_w(const float* __restrict__ Wq, const float* __restrict__ Wk,
                        const float* __restrict__ Wv, __hip_bfloat16* __restrict__ wt) {
  __shared__ float T[64][65];
  const int z = blockIdx.z;
  const float* W = (z == 0) ? Wq : (z == 1) ? Wk : Wv;
  __hip_bfloat16* Wd = wt + (size_t)z * 1048576;
  const int n0 = blockIdx.x * 64, k0 = blockIdx.y * 64;
  const int tx = threadIdx.x & 63, ty = threadIdx.x >> 6;
#pragma unroll
  for (int r = 0; r < 16; ++r)
    T[ty + r * 4][tx] = W[(size_t)(k0 + ty + r * 4) * 1024 + n0 + tx];
  __syncthreads();
#pragma unroll
  for (int r = 0; r < 16; ++r)
    Wd[(size_t)(n0 + ty + r * 4) * 1024 + k0 + tx] = __float2bfloat16(T[tx][ty + r * 4]);
}

// ---------------- kernel 3: projection GEMM ----------------
__global__ __launch_bounds__(256) void k_proj(
    const __hip_bfloat16* __restrict__ xb, const __hip_bfloat16* __restrict__ wt,
    const float* __restrict__ bq, const float* __restrict__ bk, const float* __restrict__ bv,
    __hip_bfloat16* __restrict__ Qb, __hip_bfloat16* __restrict__ Kb,
    __hip_bfloat16* __restrict__ Vt) {
  __shared__ char As[8192];   // [128 rows][32 bf16] = 64B rows
  __shared__ char Bs[8192];
  const int t = blockIdx.z;
  const char* X = (const char*)(xb + (size_t)t * 4194304);
  const char* W = (const char*)(wt + (size_t)t * 1048576);
  const float* bias = (t == 0) ? bq : (t == 1) ? bk : bv;
  const int m0 = blockIdx.y * 128, n0 = blockIdx.x * 128;
  const int tid = threadIdx.x, w = tid >> 6, lane = tid & 63;
  const int r_in = lane >> 2;
  const int cswz = (((lane & 3) ^ ((lane >> 2) & 3)) << 4);
  const int wm = (w >> 1) * 64, wn = (w & 1) * 64;
  f32x4 acc[4][4];
#pragma unroll
  for (int i = 0; i < 4; ++i)
#pragma unroll
    for (int j = 0; j < 4; ++j) acc[i][j] = (f32x4){0.f, 0.f, 0.f, 0.f};

  for (int k0 = 0; k0 < 1024; k0 += 32) {
    __syncthreads();
#pragma unroll
    for (int j = 0; j < 2; ++j) {
      const int ch = w * 2 + j;
      gload16(X + (size_t)(m0 + ch * 16 + r_in) * 2048 + k0 * 2 + cswz, As + ch * 1024);
      gload16(W + (size_t)(n0 + ch * 16 + r_in) * 2048 + k0 * 2 + cswz, Bs + ch * 1024);
    }
    __syncthreads();
    short8 af[4], bf_[4];
#pragma unroll
    for (int mt = 0; mt < 4; ++mt) {
      const int row = wm + mt * 16 + (lane & 15);
      af[mt] = *(const short8*)(As + row * 64 + (((lane >> 4) * 16) ^ ((row & 3) << 4)));
    }
#pragma unroll
    for (int nt = 0; nt < 4; ++nt) {
      const int row = wn + nt * 16 + (lane & 15);
      bf_[nt] = *(const short8*)(Bs + row * 64 + (((lane >> 4) * 16) ^ ((row & 3) << 4)));
    }
#pragma unroll
    for (int mt = 0; mt < 4; ++mt)
#pragma unroll
      for (int nt = 0; nt < 4; ++nt)
        acc[mt][nt] = __builtin_amdgcn_mfma_f32_16x16x32_bf16(af[mt], bf_[nt], acc[mt][nt], 0, 0, 0);
  }

  float bv4[4];
#pragma unroll
  for (int nt = 0; nt < 4; ++nt) bv4[nt] = bias[n0 + wn + nt * 16 + (lane & 15)];
#pragma unroll
  for (int mt = 0; mt < 4; ++mt) {
#pragma unroll
    for (int nt = 0; nt < 4; ++nt) {
      const int feat = n0 + wn + nt * 16 + (lane & 15);
      const int h = feat >> 6, d = feat & 63;
#pragma unroll
      for (int r = 0; r < 4; ++r) {
        const int token = m0 + wm + mt * 16 + (lane >> 4) * 4 + r;
        const int b = token >> 11, s = token & 2047;
        const float val = acc[mt][nt][r] + bv4[nt];
        const __hip_bfloat16 hb = __float2bfloat16(val);
        if (t == 0)      Qb[((size_t)(b * 16 + h) * 2048 + s) * 64 + d] = hb;
        else if (t == 1) Kb[((size_t)(b * 16 + h) * 2048 + s) * 64 + d] = hb;
        else             Vt[((size_t)(b * 16 + h) * 64 + d) * 2048 + s] = hb;
      }
    }
  }
}

// ---------------- kernel 4: flash attention (r2-verified 16x16 mappings) --------
// 512 blocks (XCD-swizzled), 4 waves x 32 q (2 x 16-q tiles), KVBLK=64.
// K-tile in REGISTERS (global b128, same element map as r2's LDS path).
// QK^T: s = mfma_16x16x32(Kfrag, Qfrag) -> D[key=g*4+r][q=lane&15]  (r2-verified).
// PV:   O^T[d][q] += mfma16(Vfrag, Pfrag), P packed from C/D regs   (r2-verified).
__global__ __launch_bounds__(256, 2) void k_attn(
    const __hip_bfloat16* __restrict__ Qb, const __hip_bfloat16* __restrict__ Kb,
    const __hip_bfloat16* __restrict__ Vt, const int* __restrict__ mask,
    float* __restrict__ out) {
  __shared__ char Vs[2][8192];              // [64 d][64 keys] bf16, 128B rows, swizzled
  const int orig = blockIdx.x;
  const int swz = (orig & 7) * 64 + (orig >> 3);   // XCD-contiguous (512 = 8*64, bijective)
  const int bh = swz >> 4, qb = swz & 15;
  const int b = bh >> 4, h = bh & 15;
  const int tid = threadIdx.x, w = tid >> 6, lane = tid & 63;
  const int g = lane >> 4, l15 = lane & 15;
  const int l7 = lane & 7, l8 = lane >> 3;
  const int vswz = ((l7 ^ l8) << 4);        // pre-swizzled 16B slot in 128B row
  const char* Qc = (const char*)(Qb + (size_t)bh * 131072);
  const char* Kc = (const char*)(Kb + (size_t)bh * 131072);
  const char* Vc = (const char*)(Vt + (size_t)bh * 131072);
  const int* mp = mask + b * 2048;

  // Q fragments for the wave's two 16-q tiles (r2 mapping)
  short8 aq[2][2];
#pragma unroll
  for (int i = 0; i < 2; ++i) {
    const int qrow = qb * 128 + w * 32 + i * 16 + l15;
#pragma unroll
    for (int kc = 0; kc < 2; ++kc)
      aq[i][kc] = *(const short8*)(Qc + (size_t)qrow * 128 + kc * 64 + g * 16);
  }

  // K register tile for current kt: kr[nt*2+kc] = K[key=nt*16+l15][k=kc*32+g*8 ..+7]
  const char* kbase = Kc + (size_t)l15 * 128 + g * 16;
  short8 kr[8];
#pragma unroll
  for (int nt = 0; nt < 4; ++nt)
#pragma unroll
    for (int kc = 0; kc < 2; ++kc)
      kr[nt * 2 + kc] = *(const short8*)(kbase + nt * 2048 + kc * 64);

  f32x4 oacc[2][4];
#pragma unroll
  for (int i = 0; i < 2; ++i)
#pragma unroll
    for (int dt = 0; dt < 4; ++dt) oacc[i][dt] = (f32x4){0.f, 0.f, 0.f, 0.f};
  float m2[2]   = {-__builtin_inff(), -__builtin_inff()};
  float lsum[2] = {0.f, 0.f};

  // prologue: stage V tile 0 (8 chunks, 2 per wave)
#pragma unroll
  for (int j = 0; j < 2; ++j) {
    const int ch = w * 2 + j;
    gload16(Vc + (size_t)(ch * 8 + l8) * 4096 + vswz, Vs[0] + ch * 1024);
  }
  __syncthreads();

  int cur = 0;
  for (int kt = 0; kt < 32; ++kt) {
    // mask for current tile (keys nt*16 + g*4 + r, matching C/D rows)
    union M4 { int4 v; int i[4]; };
    M4 mv[4];
#pragma unroll
    for (int nt = 0; nt < 4; ++nt)
      mv[nt].v = *(const int4*)(mp + kt * 64 + nt * 16 + g * 4);

    // QK^T from registers: 16 x mfma_f32_16x16x32_bf16
    f32x4 sc_[2][4];
    __builtin_amdgcn_s_setprio(1);
#pragma unroll
    for (int i = 0; i < 2; ++i)
#pragma unroll
      for (int nt = 0; nt < 4; ++nt) {
        f32x4 s = (f32x4){0.f, 0.f, 0.f, 0.f};
#pragma unroll
        for (int kc = 0; kc < 2; ++kc)
          s = __builtin_amdgcn_mfma_f32_16x16x32_bf16(kr[nt * 2 + kc], aq[i][kc], s, 0, 0, 0);
        sc_[i][nt] = s;
      }
    __builtin_amdgcn_s_setprio(0);

    // kr consumed -> reload in place for kt+1; stage V tile kt+1 into buf^1
    if (kt < 31) {
      const char* kb2 = kbase + (size_t)(kt + 1) * 8192;
#pragma unroll
      for (int nt = 0; nt < 4; ++nt)
#pragma unroll
        for (int kc = 0; kc < 2; ++kc)
          kr[nt * 2 + kc] = *(const short8*)(kb2 + nt * 2048 + kc * 64);
#pragma unroll
      for (int j = 0; j < 2; ++j) {
        const int ch = w * 2 + j;
        gload16(Vc + (size_t)(ch * 8 + l8) * 4096 + (kt + 1) * 128 + vswz,
                Vs[cur ^ 1] + ch * 1024);
      }
    }

    // softmax per q-tile (lane-local q = l15; reduce across 4 g-copies via shfl)
    short4v pb[2][4];
#pragma unroll
    for (int i = 0; i < 2; ++i) {
      float x[4][4];
#pragma unroll
      for (int nt = 0; nt < 4; ++nt) {
        x[nt][0] = mv[nt].i[0] ? sc_[i][nt][0] * SC_L2E : -1e30f;
        x[nt][1] = mv[nt].i[1] ? sc_[i][nt][1] * SC_L2E : -1e30f;
        x[nt][2] = mv[nt].i[2] ? sc_[i][nt][2] * SC_L2E : -1e30f;
        x[nt][3] = mv[nt].i[3] ? sc_[i][nt][3] * SC_L2E : -1e30f;
      }
      float tmax = x[0][0];
#pragma unroll
      for (int nt = 0; nt < 4; ++nt)
#pragma unroll
        for (int r = 0; r < 4; ++r) tmax = fmaxf(tmax, x[nt][r]);
      tmax = fmaxf(tmax, __shfl_xor(tmax, 16));
      tmax = fmaxf(tmax, __shfl_xor(tmax, 32));

      if (!__all(tmax <= m2[i] + 8.0f)) {
        const float mn = fmaxf(fmaxf(m2[i], tmax), -1e9f);
        const float corr = EXP2F(m2[i] - mn);
        m2[i] = mn;
        lsum[i] *= corr;
#pragma unroll
        for (int dt = 0; dt < 4; ++dt) {
#pragma unroll
          for (int r = 0; r < 4; ++r) oacc[i][dt][r] *= corr;
        }
      }

      float ps = 0.f;
#pragma unroll
      for (int nt = 0; nt < 4; ++nt) {
        union { short4v s4; __hip_bfloat16 hh[4]; } pu;
#pragma unroll
        for (int r = 0; r < 4; ++r) {
          const float e = EXP2F(x[nt][r] - m2[i]);
          ps += e;
          pu.hh[r] = __float2bfloat16(e);
        }
        pb[i][nt] = pu.s4;
      }
      ps += __shfl_xor(ps, 16);
      ps += __shfl_xor(ps, 32);
      lsum[i] += ps;
    }

    // PV: V fragments shared across both q-tiles; 32 x mfma16 (r2 mapping)
    const char* Vl = Vs[cur];
    __builtin_amdgcn_s_setprio(1);
#pragma unroll
    for (int dt = 0; dt < 4; ++dt) {
      const int vrow = dt * 16 + l15;
      short4v vf[4];
#pragma unroll
      for (int nt = 0; nt < 4; ++nt)
        vf[nt] = *(const short4v*)(Vl + vrow * 128 +
                                   ((nt * 32 + g * 8) ^ ((vrow & 7) << 4)));
#pragma unroll
      for (int i = 0; i < 2; ++i)
#pragma unroll
        for (int nt = 0; nt < 4; ++nt)
          oacc[i][dt] = mfma16(vf[nt], pb[i][nt], oacc[i][dt]);
    }
    __builtin_amdgcn_s_setprio(0);

    __syncthreads();                        // buf^1 staged (drains kr loads too)
    cur ^= 1;
  }

  // epilogue: per q-tile, O rows d -> contiguous float4 per dt for lane's q row
#pragma unroll
  for (int i = 0; i < 2; ++i) {
    const float rl = 1.0f / lsum[i];
    const int qrow = qb * 128 + w * 32 + i * 16 + l15;
    float* orow = out + ((size_t)(b * 2048 + qrow)) * 1024 + h * 64;
#pragma unroll
    for (int dt = 0; dt < 4; ++dt) {
      float4 st;
      st.x = oacc[i][dt][0] * rl; st.y = oacc[i][dt][1] * rl;
      st.z = oacc[i][dt][2] * rl; st.w = oacc[i][dt][3] * rl;
      *(float4*)(orow + dt * 16 + g * 4) = st;
    }
  }
}

// ---------------- launcher ----------------
extern "C" void kernel_launch(void* const* d_in, const int* in_sizes, int n_in,
                              void* d_out, int out_size, void* d_ws, size_t ws_size,
                              hipStream_t stream) {
  const float* q   = (const float*)d_in[0];
  const float* k   = (const float*)d_in[1];
  const float* v   = (const float*)d_in[2];
  const int* mask  = (const int*)d_in[3];
  const float* Wq  = (const float*)d_in[4];
  const float* bq  = (const float*)d_in[5];
  const float* Wk  = (const float*)d_in[6];
  const float* bk  = (const float*)d_in[7];
  const float* Wv  = (const float*)d_in[8];
  const float* bv  = (const float*)d_in[9];
  float* out = (float*)d_out;
  char* ws = (char*)d_ws;
  __hip_bfloat16* Xb = (__hip_bfloat16*)(ws);
  __hip_bfloat16* Wt = (__hip_bfloat16*)(ws + 25165824);
  __hip_bfloat16* Qb = (__hip_bfloat16*)(ws + 31457280);
  __hip_bfloat16* Kb = (__hip_bfloat16*)(ws + 39845888);
  __hip_bfloat16* Vt = (__hip_bfloat16*)(ws + 48234496);

  k_cvt_qkv<<<dim3(6144), dim3(256), 0, stream>>>(q, k, v, Xb);
  k_cvt_w<<<dim3(16, 16, 3), dim3(256), 0, stream>>>(Wq, Wk, Wv, Wt);
  k_proj<<<dim3(8, 32, 3), dim3(256), 0, stream>>>(Xb, Wt, bq, bk, bv, Qb, Kb, Vt);
  k_attn<<<dim3(512), dim3(256), 0, stream>>>(Qb, Kb, Vt, mask, out);
}